// Round 1
// baseline (150.016 us; speedup 1.0000x reference)
//
#include <hip/hip_runtime.h>
#include <hip/hip_bf16.h>

typedef unsigned short ushort_t;
typedef __attribute__((ext_vector_type(4))) float f32x4;
typedef __attribute__((ext_vector_type(8))) short bf16x8;
typedef __attribute__((ext_vector_type(8))) unsigned short u16x8;

#define M_DIM 2048
#define N_DIM 4096
#define K_DIM 4096

// ---------- helpers ----------
__device__ __forceinline__ unsigned short f2bf(float f) {
  unsigned int u = __float_as_uint(f);
  u += 0x7FFFu + ((u >> 16) & 1u);   // round-to-nearest-even
  return (unsigned short)(u >> 16);
}

__device__ __forceinline__ void async16(void* l, const void* g) {
  __builtin_amdgcn_global_load_lds(
      (const __attribute__((address_space(1))) void*)g,
      (__attribute__((address_space(3))) void*)l,
      16, 0, 0);
}

// ---------- kernel 1: x fp32 -> bf16 ----------
__global__ void k_f32_to_bf16(const float* __restrict__ x, ushort_t* __restrict__ o, int n4) {
  int i = blockIdx.x * blockDim.x + threadIdx.x;
  int st = gridDim.x * blockDim.x;
  for (; i < n4; i += st) {
    float4 v = ((const float4*)x)[i];
    ushort4 r;
    r.x = f2bf(v.x); r.y = f2bf(v.y); r.z = f2bf(v.z); r.w = f2bf(v.w);
    ((ushort4*)o)[i] = r;
  }
}

// ---------- kernel 2: T01[i1,o1,i2,o2,r] = sum_q core0[i1,o1,q]*core1[q,i2,o2,r] ----------
__global__ void k_build_t01(const float* __restrict__ c0, const float* __restrict__ c1,
                            float* __restrict__ t01) {
  int idx = blockIdx.x * 256 + threadIdx.x;   // 1M threads
  int r  = idx & 15;
  int o2 = (idx >> 4) & 15;
  int i2 = (idx >> 8) & 15;
  int o1 = (idx >> 12) & 15;
  int i1 = (idx >> 16) & 15;
  const float* c0p = c0 + (i1 * 16 + o1) * 16;          // + q
  const float* c1p = c1 + (i2 * 16 + o2) * 16 + r;      // + q*4096
  float s = 0.f;
  #pragma unroll
  for (int q = 0; q < 16; ++q) s += c0p[q] * c1p[q * 4096];
  t01[idx] = s;
}

// ---------- kernel 3: Wt[out][in] bf16, out=(o1,o2,o3), in=(i1,i2,i3) ----------
// Wt[out][in] = sum_r T01[i1,o1,i2,o2,r] * core2[r,i3,o3]
__global__ void k_build_wt(const float* __restrict__ t01, const float* __restrict__ c2,
                           ushort_t* __restrict__ wt) {
  int tid = blockIdx.x * 256 + threadIdx.x;   // 1M threads, 16 outputs each
  int i2 = tid & 15;
  int i1 = (tid >> 4) & 15;
  int out = tid >> 8;                          // 0..4095
  int o3 = out & 15;
  int o2 = (out >> 4) & 15;
  int o1 = out >> 8;
  const float* tp = t01 + ((((i1 * 16 + o1) * 16 + i2) * 16 + o2) << 4);
  float t[16];
  #pragma unroll
  for (int r = 0; r < 16; ++r) t[r] = tp[r];
  u16x8 lo, hi;
  #pragma unroll
  for (int i3 = 0; i3 < 16; ++i3) {
    const float* c2p = c2 + i3 * 16 + o3;      // + r*256
    float s = 0.f;
    #pragma unroll
    for (int rr = 0; rr < 16; ++rr) s += t[rr] * c2p[rr * 256];
    ushort_t v = f2bf(s);
    if (i3 < 8) lo[i3] = v; else hi[i3 - 8] = v;
  }
  u16x8* dst = (u16x8*)(wt + ((size_t)out << 12) + (i1 << 8) + (i2 << 4));
  dst[0] = lo;
  dst[1] = hi;
}

// ---------- kernel 4: GEMM C[M][N] = A[M][K] * Wt[N][K]^T + bias ----------
// 128x128 tile, BK=64, 4 waves (each 64x64), mfma_f32_16x16x32_bf16
__global__ __launch_bounds__(256, 2) void k_gemm(
    const ushort_t* __restrict__ A,
    const ushort_t* __restrict__ Bt,
    const float* __restrict__ bias,
    float* __restrict__ C)
{
  __shared__ ushort_t lA[128 * 64];
  __shared__ ushort_t lB[128 * 64];

  const int tid = threadIdx.x;
  const int lane = tid & 63;
  const int wid = tid >> 6;
  const int wr = wid >> 1;   // wave row quadrant (0,1)
  const int wc = wid & 1;    // wave col quadrant (0,1)

  // XCD-aware swizzle: nwg=512, divisible by 8 -> bijective
  int bid = blockIdx.x;
  int swz = ((bid & 7) << 6) | (bid >> 3);
  const int bm = swz >> 5;   // 0..15
  const int bn = swz & 31;   // 0..31

  // staging addresses: wave wid covers rows wid*32 .. wid*32+31 (4 iters x 8 rows)
  const int lrow = lane >> 3;          // 0..7
  const int lk = (lane & 7) << 3;      // k element offset (8 bf16 = 16B granule)
  const ushort_t* aG = A  + (size_t)(bm * 128 + wid * 32 + lrow) * K_DIM + lk;
  const ushort_t* bG = Bt + (size_t)(bn * 128 + wid * 32 + lrow) * K_DIM + lk;

  // fragment read addresses
  const int fr = lane & 15;
  const int fg = lane >> 4;
  const ushort_t* lAf = &lA[(wr * 64 + fr) * 64 + fg * 8];
  const ushort_t* lBf = &lB[(wc * 64 + fr) * 64 + fg * 8];

  f32x4 acc[4][4];
  #pragma unroll
  for (int m = 0; m < 4; ++m)
    #pragma unroll
    for (int n = 0; n < 4; ++n)
      acc[m][n] = (f32x4){0.f, 0.f, 0.f, 0.f};

  for (int ks = 0; ks < K_DIM / 64; ++ks) {
    __syncthreads();   // previous tile fully consumed
    #pragma unroll
    for (int it = 0; it < 4; ++it) {
      async16(&lA[(wid * 4 + it) * 512], aG + (size_t)it * 8 * K_DIM);
      async16(&lB[(wid * 4 + it) * 512], bG + (size_t)it * 8 * K_DIM);
    }
    aG += 64; bG += 64;
    __syncthreads();   // compiler drains vmcnt(0) before barrier -> tile resident

    #pragma unroll
    for (int kk = 0; kk < 2; ++kk) {
      bf16x8 af[4], bfr[4];
      #pragma unroll
      for (int m = 0; m < 4; ++m) af[m] = *(const bf16x8*)(lAf + m * 16 * 64 + kk * 32);
      #pragma unroll
      for (int n = 0; n < 4; ++n) bfr[n] = *(const bf16x8*)(lBf + n * 16 * 64 + kk * 32);
      #pragma unroll
      for (int m = 0; m < 4; ++m)
        #pragma unroll
        for (int n = 0; n < 4; ++n)
          acc[m][n] = __builtin_amdgcn_mfma_f32_16x16x32_bf16(af[m], bfr[n], acc[m][n], 0, 0, 0);
    }
  }

  // epilogue: C/D layout col = lane&15, row = (lane>>4)*4 + reg  [verified m89/m91]
  const size_t row0 = (size_t)bm * 128 + wr * 64;
  const int col0 = bn * 128 + wc * 64;
  #pragma unroll
  for (int n = 0; n < 4; ++n) {
    const int col = col0 + n * 16 + fr;
    const float bv = bias[col];
    #pragma unroll
    for (int m = 0; m < 4; ++m) {
      const size_t r0 = row0 + m * 16 + fg * 4;
      #pragma unroll
      for (int r = 0; r < 4; ++r)
        C[(r0 + r) * N_DIM + col] = acc[m][n][r] + bv;
    }
  }
}

// ---------- launch ----------
extern "C" void kernel_launch(void* const* d_in, const int* in_sizes, int n_in,
                              void* d_out, int out_size, void* d_ws, size_t ws_size,
                              hipStream_t stream) {
  const float* x    = (const float*)d_in[0];
  const float* c0   = (const float*)d_in[1];
  const float* c1   = (const float*)d_in[2];
  const float* c2   = (const float*)d_in[3];
  const float* bias = (const float*)d_in[4];
  float* out = (float*)d_out;

  // workspace layout: Abf 16MB | Wt 32MB | T01 4MB  => 52MB needed
  const size_t NEED = (size_t)52 * 1024 * 1024;
  if (ws_size < NEED) return;  // visible failure rather than OOB corruption

  char* ws = (char*)d_ws;
  ushort_t* Abf = (ushort_t*)ws;
  ushort_t* Wt  = (ushort_t*)(ws + (size_t)16 * 1024 * 1024);
  float*    T01 = (float*)(ws + (size_t)48 * 1024 * 1024);

  k_f32_to_bf16<<<2048, 256, 0, stream>>>(x, Abf, (M_DIM * K_DIM) / 4);
  k_build_t01 <<<4096, 256, 0, stream>>>(c0, c1, T01);
  k_build_wt  <<<4096, 256, 0, stream>>>(T01, c2, Wt);
  k_gemm      <<<512, 256, 0, stream>>>(Abf, Wt, bias, out);
}

// Round 2
// 145.435 us; speedup vs baseline: 1.0315x; 1.0315x over previous
//
#include <hip/hip_runtime.h>
#include <hip/hip_bf16.h>

typedef unsigned short ushort_t;
typedef __attribute__((ext_vector_type(4))) float f32x4;
typedef __attribute__((ext_vector_type(8))) short bf16x8;
typedef __attribute__((ext_vector_type(8))) unsigned short u16x8;

#define M_DIM 2048
#define N_DIM 4096
#define K_DIM 4096
#define BM 256
#define BN 128
#define BK 64
#define NT (K_DIM / BK)   // 64 K-tiles

// ---------- helpers ----------
__device__ __forceinline__ unsigned short f2bf(float f) {
  unsigned int u = __float_as_uint(f);
  u += 0x7FFFu + ((u >> 16) & 1u);   // round-to-nearest-even
  return (unsigned short)(u >> 16);
}

__device__ __forceinline__ void async16(void* l, const void* g) {
  __builtin_amdgcn_global_load_lds(
      (const __attribute__((address_space(1))) void*)g,
      (__attribute__((address_space(3))) void*)l,
      16, 0, 0);
}

// ---------- kernel 1: x fp32 -> bf16 ----------
__global__ void k_f32_to_bf16(const float* __restrict__ x, ushort_t* __restrict__ o, int n4) {
  int i = blockIdx.x * blockDim.x + threadIdx.x;
  int st = gridDim.x * blockDim.x;
  for (; i < n4; i += st) {
    float4 v = ((const float4*)x)[i];
    ushort4 r;
    r.x = f2bf(v.x); r.y = f2bf(v.y); r.z = f2bf(v.z); r.w = f2bf(v.w);
    ((ushort4*)o)[i] = r;
  }
}

// ---------- kernel 2: T01[i1,o1,i2,o2,r] = sum_q core0[i1,o1,q]*core1[q,i2,o2,r] ----------
__global__ void k_build_t01(const float* __restrict__ c0, const float* __restrict__ c1,
                            float* __restrict__ t01) {
  int idx = blockIdx.x * 256 + threadIdx.x;   // 1M threads
  int r  = idx & 15;
  int o2 = (idx >> 4) & 15;
  int i2 = (idx >> 8) & 15;
  int o1 = (idx >> 12) & 15;
  int i1 = (idx >> 16) & 15;
  const float* c0p = c0 + (i1 * 16 + o1) * 16;          // + q
  const float* c1p = c1 + (i2 * 16 + o2) * 16 + r;      // + q*4096
  float s = 0.f;
  #pragma unroll
  for (int q = 0; q < 16; ++q) s += c0p[q] * c1p[q * 4096];
  t01[idx] = s;
}

// ---------- kernel 3: Wt[out][in] bf16, out=(o1,o2,o3), in=(i1,i2,i3) ----------
__global__ void k_build_wt(const float* __restrict__ t01, const float* __restrict__ c2,
                           ushort_t* __restrict__ wt) {
  int tid = blockIdx.x * 256 + threadIdx.x;   // 1M threads, 16 outputs each
  int i2 = tid & 15;
  int i1 = (tid >> 4) & 15;
  int out = tid >> 8;                          // 0..4095
  int o3 = out & 15;
  int o2 = (out >> 4) & 15;
  int o1 = out >> 8;
  const float* tp = t01 + ((((i1 * 16 + o1) * 16 + i2) * 16 + o2) << 4);
  float t[16];
  #pragma unroll
  for (int r = 0; r < 16; ++r) t[r] = tp[r];
  u16x8 lo, hi;
  #pragma unroll
  for (int i3 = 0; i3 < 16; ++i3) {
    const float* c2p = c2 + i3 * 16 + o3;      // + r*256
    float s = 0.f;
    #pragma unroll
    for (int rr = 0; rr < 16; ++rr) s += t[rr] * c2p[rr * 256];
    ushort_t v = f2bf(s);
    if (i3 < 8) lo[i3] = v; else hi[i3 - 8] = v;
  }
  u16x8* dst = (u16x8*)(wt + ((size_t)out << 12) + (i1 << 8) + (i2 << 4));
  dst[0] = lo;
  dst[1] = hi;
}

// ---------- kernel 4: GEMM C[M][N] = A[M][K] * Wt[N][K]^T + bias ----------
// BM=256 BN=128 BK=64, 512 threads (8 waves 4Mx2N, 64x64 each),
// triple-buffered LDS, counted vmcnt(12), raw s_barrier, T2 swizzle, T5 setprio.
__global__ __launch_bounds__(512, 2) void k_gemm(
    const ushort_t* __restrict__ A,
    const ushort_t* __restrict__ Bt,
    const float* __restrict__ bias,
    float* __restrict__ C)
{
  __shared__ ushort_t lA[3][BM * BK];   // 3 x 32KB
  __shared__ ushort_t lB[3][BN * BK];   // 3 x 16KB   (total 144KB)

  const int tid  = threadIdx.x;
  const int lane = tid & 63;
  const int wid  = tid >> 6;     // 0..7
  const int wm   = wid >> 1;     // 0..3  (M quadrant, 64 rows)
  const int wn   = wid & 1;      // 0..1  (N half, 64 cols)
  const int fr   = lane & 15;
  const int fg   = lane >> 4;    // 0..3

  // XCD swizzle: 256 wgs; bm = bid&7 -> each XCD owns one A-panel (2MB, L2-fit)
  const int bid = blockIdx.x;
  const int bm  = bid & 7;       // 0..7
  const int bn  = bid >> 3;      // 0..31

  // ---- staging addresses (T2: linear LDS dest + inverse-swizzled global source) ----
  const int srow = tid >> 3;                               // 0..63 within a 64-row round
  const int scol = ((tid & 7) ^ (srow & 7)) << 3;          // swizzled source k-offset (elems)
  const ushort_t* aSt = A  + (size_t)(bm * BM + srow) * K_DIM + scol;
  const ushort_t* bSt = Bt + (size_t)(bn * BN + srow) * K_DIM + scol;
  const int dE = tid * 8;                                  // linear dest elems per round

#define STAGE(kt, s) do {                                                        \
    _Pragma("unroll")                                                            \
    for (int r_ = 0; r_ < 4; ++r_)                                               \
      async16(&lA[s][r_ * 4096 + dE], aSt + (size_t)(kt) * BK + (size_t)r_ * 64 * K_DIM); \
    _Pragma("unroll")                                                            \
    for (int r_ = 0; r_ < 2; ++r_)                                               \
      async16(&lB[s][r_ * 4096 + dE], bSt + (size_t)(kt) * BK + (size_t)r_ * 64 * K_DIM); \
  } while (0)

  // ---- fragment read addressing (swizzled on read) ----
  const int arowb = wm * 64 + fr;                // + m*16
  const int browb = wn * 64 + fr;                // + n*16
  const int c0 = ( fg      ^ (fr & 7)) << 3;     // kk=0 col bytes/2
  const int c1 = ((fg + 4) ^ (fr & 7)) << 3;     // kk=1

  f32x4 acc[4][4];
  #pragma unroll
  for (int m = 0; m < 4; ++m)
    #pragma unroll
    for (int n = 0; n < 4; ++n)
      acc[m][n] = (f32x4){0.f, 0.f, 0.f, 0.f};

  STAGE(0, 0);
  STAGE(1, 1);
  int ss = 2, sc = 0;

  for (int t = 0; t < NT; ++t) {
    if (t + 2 < NT) {
      STAGE(t + 2, ss);
      ss = (ss == 2) ? 0 : ss + 1;
    }
    if (t + 2 < NT)      asm volatile("s_waitcnt vmcnt(12)" ::: "memory");
    else if (t + 1 < NT) asm volatile("s_waitcnt vmcnt(6)"  ::: "memory");
    else                 asm volatile("s_waitcnt vmcnt(0)"  ::: "memory");
    __builtin_amdgcn_s_barrier();          // tile t resident for all waves
    __builtin_amdgcn_sched_barrier(0);     // no ds_read hoists above this point

    {
      const ushort_t* pA = lA[sc];
      const ushort_t* pB = lB[sc];
      bf16x8 af[4][2], bfv[4][2];
      #pragma unroll
      for (int m = 0; m < 4; ++m) {
        af[m][0] = *(const bf16x8*)(pA + (arowb + m * 16) * 64 + c0);
        af[m][1] = *(const bf16x8*)(pA + (arowb + m * 16) * 64 + c1);
      }
      #pragma unroll
      for (int n = 0; n < 4; ++n) {
        bfv[n][0] = *(const bf16x8*)(pB + (browb + n * 16) * 64 + c0);
        bfv[n][1] = *(const bf16x8*)(pB + (browb + n * 16) * 64 + c1);
      }
      __builtin_amdgcn_s_setprio(1);
      #pragma unroll
      for (int kk = 0; kk < 2; ++kk)
        #pragma unroll
        for (int m = 0; m < 4; ++m)
          #pragma unroll
          for (int n = 0; n < 4; ++n)
            acc[m][n] = __builtin_amdgcn_mfma_f32_16x16x32_bf16(af[m][kk], bfv[n][kk],
                                                                acc[m][n], 0, 0, 0);
      __builtin_amdgcn_s_setprio(0);
    }

    __builtin_amdgcn_sched_barrier(0);     // keep compute inside the barrier pair
    __builtin_amdgcn_s_barrier();          // all reads of slot sc done before restage
    sc = (sc == 2) ? 0 : sc + 1;
  }
#undef STAGE

  // epilogue: C/D layout col = lane&15, row = (lane>>4)*4 + reg
  const size_t row0 = (size_t)bm * BM + wm * 64;
  const int col0 = bn * BN + wn * 64;
  #pragma unroll
  for (int n = 0; n < 4; ++n) {
    const int col = col0 + n * 16 + fr;
    const float bv = bias[col];
    #pragma unroll
    for (int m = 0; m < 4; ++m) {
      const size_t r0 = row0 + m * 16 + fg * 4;
      #pragma unroll
      for (int r = 0; r < 4; ++r)
        C[(r0 + r) * N_DIM + col] = acc[m][n][r] + bv;
    }
  }
}

// ---------- launch ----------
extern "C" void kernel_launch(void* const* d_in, const int* in_sizes, int n_in,
                              void* d_out, int out_size, void* d_ws, size_t ws_size,
                              hipStream_t stream) {
  const float* x    = (const float*)d_in[0];
  const float* c0   = (const float*)d_in[1];
  const float* c1   = (const float*)d_in[2];
  const float* c2   = (const float*)d_in[3];
  const float* bias = (const float*)d_in[4];
  float* out = (float*)d_out;

  // workspace layout: Abf 16MB | Wt 32MB | T01 4MB  => 52MB needed
  const size_t NEED = (size_t)52 * 1024 * 1024;
  if (ws_size < NEED) return;

  char* ws = (char*)d_ws;
  ushort_t* Abf = (ushort_t*)ws;
  ushort_t* Wt  = (ushort_t*)(ws + (size_t)16 * 1024 * 1024);
  float*    T01 = (float*)(ws + (size_t)48 * 1024 * 1024);

  k_f32_to_bf16<<<2048, 256, 0, stream>>>(x, Abf, (M_DIM * K_DIM) / 4);
  k_build_t01 <<<4096, 256, 0, stream>>>(c0, c1, T01);
  k_build_wt  <<<4096, 256, 0, stream>>>(T01, c2, Wt);
  k_gemm      <<<256, 512, 0, stream>>>(Abf, Wt, bias, out);
}